// Round 5
// baseline (262.567 us; speedup 1.0000x reference)
//
#include <hip/hip_runtime.h>
#include <hip/hip_bf16.h>

typedef unsigned short u16;
typedef __attribute__((ext_vector_type(8))) short short8;
typedef __attribute__((ext_vector_type(8))) unsigned short ushort8;
typedef __attribute__((ext_vector_type(4))) float f32x4;
typedef __attribute__((ext_vector_type(4))) float f4;

#define GLB_CAST(p) ((const __attribute__((address_space(1))) unsigned int*)(p))
#define LDS_CAST(p) ((__attribute__((address_space(3))) unsigned int*)(p))

__device__ __forceinline__ void gl_lds16(const void* g, void* l) {
  __builtin_amdgcn_global_load_lds(GLB_CAST(g), LDS_CAST(l), 16, 0, 0);
}

__device__ __forceinline__ u16 f2bf(float f) {
  __hip_bfloat16 b = __float2bfloat16(f);           // RNE
  return __builtin_bit_cast(u16, b);
}

// ---------------- prep: W [R][C] f32 -> Wt [C][R] bf16 ----------------
__global__ void transpose_cvt_k(const float* __restrict__ in,
                                u16* __restrict__ out, int R, int C) {
  __shared__ float tile[32][33];
  int c0 = blockIdx.x * 32, r0 = blockIdx.y * 32;
  int tx = threadIdx.x, ty = threadIdx.y;     // 32 x 8
#pragma unroll
  for (int i = 0; i < 32; i += 8)
    tile[ty + i][tx] = in[(size_t)(r0 + ty + i) * C + c0 + tx];
  __syncthreads();
#pragma unroll
  for (int i = 0; i < 32; i += 8)
    out[(size_t)(c0 + ty + i) * R + r0 + tx] = f2bf(tile[tx][ty + i]);
}

// ================= GEMM1: A-resident, barrier-free K-loop =================
// Block: 512 thr (8 waves, 2wr x 4wc), owns m-tile [128 x K384] staged ONCE in
// LDS (f32->bf16, XOR-swizzled). Loops over 3 regions (q,k,v) x 6 K-steps;
// B fragments read directly global->VGPR (w1T is L2-resident, 884KB).
// Single __syncthreads per block. Outputs all row-major [b,h,t,d] bf16.
__global__ __launch_bounds__(512, 2) void gemm_qkv_k(
    const float* __restrict__ X, const u16* __restrict__ Bt,
    const float* __restrict__ bias,
    u16* __restrict__ oQ, u16* __restrict__ oK, u16* __restrict__ oV) {
  __shared__ u16 As[128 * 384];   // 96KB
  const int tid = threadIdx.x;
  const int m0 = blockIdx.x * 128;

  // ---- stage A once: 6144 16B-chunks, swizzled write ----
#pragma unroll
  for (int i = 0; i < 12; ++i) {
    int c = tid + i * 512;
    int row = c / 48, cc = c % 48;
    const float* src = X + (size_t)(m0 + row) * 384 + cc * 8;
    f4 a = *(const f4*)src;
    f4 b = *(const f4*)(src + 4);
    ushort8 o;
#pragma unroll
    for (int j = 0; j < 4; ++j) { o[j] = f2bf(a[j]); o[4 + j] = f2bf(b[j]); }
    *(ushort8*)((char*)As + row * 768 + ((cc * 16) ^ ((row & 7) << 4))) = o;
  }
  __syncthreads();   // the only barrier

  const int lane = tid & 63, wid = tid >> 6;
  const int lo = lane & 15, hi = lane >> 4;
  const int wr = wid >> 2, wc = wid & 3;     // 2 x 4 -> wave = 64m x 96n
  const int akey = (lo & 7) << 4;            // (arow&7) == (lo&7) for all m

  // A-frag LDS base bytes (per m)
  int abase[4];
#pragma unroll
  for (int m = 0; m < 4; ++m) abase[m] = (wr * 64 + m * 16 + lo) * 768;

  // epilogue row-part: gm = m0 + wr*64 + m*16 + hi*4 + rr
  int rp[4][4];
#pragma unroll
  for (int m = 0; m < 4; ++m)
#pragma unroll
    for (int rr = 0; rr < 4; ++rr) {
      int gm = m0 + wr * 64 + m * 16 + hi * 4 + rr;
      rp[m][rr] = (gm >> 8) * 98304 + (gm & 255) * 64;   // b*6*16384 + t*64
    }

#pragma unroll
  for (int reg = 0; reg < 3; ++reg) {
    const u16* bp[6];
    float bb[6];
    int cp[6];
#pragma unroll
    for (int n = 0; n < 6; ++n) {
      int col = wc * 96 + n * 16 + lo;
      bp[n] = Bt + (size_t)(reg * 384 + col) * 384;
      bb[n] = bias[reg * 384 + col];
      cp[n] = (col >> 6) * 16384 + (col & 63);           // hh*16384 + d
    }

    f32x4 acc[4][6];
    const f32x4 Z4 = {0.f, 0.f, 0.f, 0.f};
#pragma unroll
    for (int m = 0; m < 4; ++m)
#pragma unroll
      for (int n = 0; n < 6; ++n) acc[m][n] = Z4;

#pragma unroll 2
    for (int kt = 0; kt < 6; ++kt) {
      short8 bf[6][2];
#pragma unroll
      for (int n = 0; n < 6; ++n)
#pragma unroll
        for (int s = 0; s < 2; ++s)
          bf[n][s] = *(const short8*)(bp[n] + kt * 64 + s * 32 + hi * 8);
      short8 af[4][2];
#pragma unroll
      for (int m = 0; m < 4; ++m)
#pragma unroll
        for (int s = 0; s < 2; ++s)
          af[m][s] = *(const short8*)((const char*)As + abase[m] +
                                      ((kt * 128 + s * 64 + hi * 16) ^ akey));
#pragma unroll
      for (int s = 0; s < 2; ++s)
#pragma unroll
        for (int m = 0; m < 4; ++m)
#pragma unroll
          for (int n = 0; n < 6; ++n)
            acc[m][n] = __builtin_amdgcn_mfma_f32_16x16x32_bf16(
                af[m][s], bf[n][s], acc[m][n], 0, 0, 0);
    }

    u16* dst = (reg == 0) ? oQ : ((reg == 1) ? oK : oV);
#pragma unroll
    for (int m = 0; m < 4; ++m)
#pragma unroll
      for (int n = 0; n < 6; ++n)
#pragma unroll
        for (int rr = 0; rr < 4; ++rr)
          dst[(size_t)(rp[m][rr] + cp[n])] = f2bf(acc[m][n][rr] + bb[n]);
  }
}

// ================= GEMM2: same structure, bf16 A via global_load_lds =================
__global__ __launch_bounds__(512, 2) void gemm_proj_k(
    const u16* __restrict__ A, const u16* __restrict__ Bt,
    const float* __restrict__ bias, float* __restrict__ oF) {
  __shared__ u16 As[128 * 384];   // 96KB
  const int tid = threadIdx.x;
  const int m0 = blockIdx.x * 128;

  // stage A once: linear LDS dest, inverse-swizzled global source (rule #21)
#pragma unroll
  for (int i = 0; i < 12; ++i) {
    int c = tid + i * 512;
    int row = c / 48, cc = c % 48;
    int cs = cc ^ (row & 7);
    gl_lds16(A + (size_t)(m0 + row) * 384 + cs * 8, (char*)As + c * 16);
  }
  __syncthreads();   // drains vmcnt; the only barrier

  const int lane = tid & 63, wid = tid >> 6;
  const int lo = lane & 15, hi = lane >> 4;
  const int wr = wid >> 2, wc = wid & 3;
  const int akey = (lo & 7) << 4;

  int abase[4];
#pragma unroll
  for (int m = 0; m < 4; ++m) abase[m] = (wr * 64 + m * 16 + lo) * 768;

  const u16* bp[6];
  float bb[6];
  int cols[6];
#pragma unroll
  for (int n = 0; n < 6; ++n) {
    int col = wc * 96 + n * 16 + lo;
    bp[n] = Bt + (size_t)col * 384;
    bb[n] = bias[col];
    cols[n] = col;
  }

  f32x4 acc[4][6];
  const f32x4 Z4 = {0.f, 0.f, 0.f, 0.f};
#pragma unroll
  for (int m = 0; m < 4; ++m)
#pragma unroll
    for (int n = 0; n < 6; ++n) acc[m][n] = Z4;

#pragma unroll 2
  for (int kt = 0; kt < 6; ++kt) {
    short8 bf[6][2];
#pragma unroll
    for (int n = 0; n < 6; ++n)
#pragma unroll
      for (int s = 0; s < 2; ++s)
        bf[n][s] = *(const short8*)(bp[n] + kt * 64 + s * 32 + hi * 8);
    short8 af[4][2];
#pragma unroll
    for (int m = 0; m < 4; ++m)
#pragma unroll
      for (int s = 0; s < 2; ++s)
        af[m][s] = *(const short8*)((const char*)As + abase[m] +
                                    ((kt * 128 + s * 64 + hi * 16) ^ akey));
#pragma unroll
    for (int s = 0; s < 2; ++s)
#pragma unroll
      for (int m = 0; m < 4; ++m)
#pragma unroll
        for (int n = 0; n < 6; ++n)
          acc[m][n] = __builtin_amdgcn_mfma_f32_16x16x32_bf16(
              af[m][s], bf[n][s], acc[m][n], 0, 0, 0);
  }

#pragma unroll
  for (int m = 0; m < 4; ++m)
#pragma unroll
    for (int rr = 0; rr < 4; ++rr) {
      int gm = m0 + wr * 64 + m * 16 + hi * 4 + rr;
#pragma unroll
      for (int n = 0; n < 6; ++n)
        oF[(size_t)gm * 384 + cols[n]] = acc[m][n][rr] + bb[n];
    }
}

// ---------------- windowed causal attention ----------------
// grid: (B*H*4) blocks; block = 4 waves; 64 queries, 128 candidate keys.
// V is now ROW-major [b,h,t,d]; transposed into Vs at staging time.
__global__ __launch_bounds__(256) void attn_k(
    const u16* __restrict__ Qb, const u16* __restrict__ Kb,
    const u16* __restrict__ Vb, const float* __restrict__ gate,
    u16* __restrict__ Ao) {
  __shared__ u16 Ks[128 * 64];      // [key][d]   swizzled, 16KB
  __shared__ u16 Vs[64 * 128];      // [d][key]   swizzled, 16KB
  __shared__ u16 Ps[4][16 * 128];   // per-wave P [q][key] swizzled, 16KB
  const int bx = blockIdx.x;
  const int qt = bx & 3, bh = bx >> 2;
  const int h = bh % 6, b = bh / 6;
  const int i0 = qt * 64, j0 = i0 - 64;
  const int tid = threadIdx.x, w = tid >> 6, lane = tid & 63;
  const int lo = lane & 15, hi = lane >> 4;

  const u16* Kh = Kb + (size_t)bh * (256 * 64);
  const u16* Vh = Vb + (size_t)bh * (256 * 64);
  const u16* Qh = Qb + (size_t)bh * (256 * 64);

  // stage K [128 x 64]: linear LDS dest, inverse-swizzled global source
#pragma unroll
  for (int it = 0; it < 4; ++it) {
    int chunk = tid + it * 256;
    int row = chunk >> 3, cc = chunk & 7;
    int csrc = cc ^ (row & 7);
    int j = j0 + row; if (j < 0) j = 0;
    gl_lds16(Kh + j * 64 + csrc * 8, Ks + chunk * 8);
  }
  // stage V row-major -> Vs[d][t] transposed+swizzled (reg round-trip)
#pragma unroll
  for (int it = 0; it < 4; ++it) {
    int c = tid + it * 256;          // [0,1024)
    int dc = c >> 7;                 // d-octet 0..7
    int j = c & 127;
    int jj = j0 + j; if (jj < 0) jj = 0;
    ushort8 v = *(const ushort8*)(Vh + jj * 64 + dc * 8);
#pragma unroll
    for (int e = 0; e < 8; ++e) {
      int d = dc * 8 + e;
      *(u16*)((char*)Vs + ((d * 256 + 2 * j) ^ ((d & 7) << 4))) = v[e];
    }
  }

  const int iq = i0 + w * 16 + lo;
  short8 aq0 = *(const short8*)(Qh + iq * 64 + hi * 8);
  short8 aq1 = *(const short8*)(Qh + iq * 64 + 32 + hi * 8);

  __syncthreads();

  const f32x4 Z4 = {0.f, 0.f, 0.f, 0.f};
  f32x4 accS[8];
#pragma unroll
  for (int t = 0; t < 8; ++t) accS[t] = Z4;
#pragma unroll
  for (int t = 0; t < 8; ++t) {
    int key = t * 16 + lo;
    int base = key * 128;
    int sw = (key & 7) << 4;
    short8 bk0 = *(const short8*)((const char*)Ks + ((base + hi * 16) ^ sw));
    short8 bk1 = *(const short8*)((const char*)Ks + ((base + 64 + hi * 16) ^ sw));
    accS[t] = __builtin_amdgcn_mfma_f32_16x16x32_bf16(aq0, bk0, accS[t], 0, 0, 0);
    accS[t] = __builtin_amdgcn_mfma_f32_16x16x32_bf16(aq1, bk1, accS[t], 0, 0, 0);
  }

  float pv[4][8];
  float rinv[4];
#pragma unroll
  for (int r = 0; r < 4; ++r) {
    int i = i0 + w * 16 + hi * 4 + r;
    float mx = -1e30f;
    float vals[8];
#pragma unroll
    for (int t = 0; t < 8; ++t) {
      int j = j0 + t * 16 + lo;
      float s = accS[t][r] * 0.125f;
      bool ok = (j >= 0) && (j <= i) && (j >= i - 64);
      vals[t] = ok ? s : -1e30f;
      mx = fmaxf(mx, vals[t]);
    }
#pragma unroll
    for (int off = 1; off < 16; off <<= 1) mx = fmaxf(mx, __shfl_xor(mx, off));
    float sum = 0.f;
#pragma unroll
    for (int t = 0; t < 8; ++t) {
      float p = __expf(vals[t] - mx);
      pv[r][t] = p;
      sum += p;
    }
#pragma unroll
    for (int off = 1; off < 16; off <<= 1) sum += __shfl_xor(sum, off);
    rinv[r] = 1.0f / sum;
  }

  u16* Pw = Ps[w];
#pragma unroll
  for (int r = 0; r < 4; ++r) {
    int ql = hi * 4 + r;
    int sw = (ql & 7) << 4;
#pragma unroll
    for (int t = 0; t < 8; ++t) {
      int off = (ql * 256 + (t * 16 + lo) * 2) ^ sw;
      *(u16*)((char*)Pw + off) = f2bf(pv[r][t]);
    }
  }

  f32x4 accO[4];
#pragma unroll
  for (int dt = 0; dt < 4; ++dt) accO[dt] = Z4;
#pragma unroll
  for (int ks = 0; ks < 4; ++ks) {
    int offA = (lo * 256 + ks * 64 + hi * 16) ^ ((lo & 7) << 4);
    short8 ap = *(const short8*)((const char*)Pw + offA);
#pragma unroll
    for (int dt = 0; dt < 4; ++dt) {
      int d = dt * 16 + lo;
      int offB = (d * 256 + ks * 64 + hi * 16) ^ ((d & 7) << 4);
      short8 bv = *(const short8*)((const char*)Vs + offB);
      accO[dt] = __builtin_amdgcn_mfma_f32_16x16x32_bf16(ap, bv, accO[dt], 0, 0, 0);
    }
  }

#pragma unroll
  for (int dt = 0; dt < 4; ++dt) {
    int d = dt * 16 + lo;
    float gg = gate[h * 64 + d];
#pragma unroll
    for (int r = 0; r < 4; ++r) {
      int i = i0 + w * 16 + hi * 4 + r;
      float v = accO[dt][r] * rinv[r] * gg;
      Ao[(size_t)(b * 256 + i) * 384 + h * 64 + d] = f2bf(v);
    }
  }
}

// ---------------- launch ----------------
extern "C" void kernel_launch(void* const* d_in, const int* in_sizes, int n_in,
                              void* d_out, int out_size, void* d_ws, size_t ws_size,
                              hipStream_t stream) {
  const float* x      = (const float*)d_in[0];
  const float* qkv_w  = (const float*)d_in[1];
  const float* qkv_b  = (const float*)d_in[2];
  const float* proj_w = (const float*)d_in[3];
  const float* proj_b = (const float*)d_in[4];
  const float* gate   = (const float*)d_in[5];
  float* out = (float*)d_out;

  // ws layout:
  //   [0, 50331648)            att (attention output, bf16)
  //   [50331648, 100663296)    v [b,h,t,d] bf16
  //   [100663296, 101548032)   w1T [1152,384] bf16
  //   [101548032, 101842944)   pT  [384,384]  bf16
  char* ws = (char*)d_ws;
  u16* att  = (u16*)ws;
  u16* vbuf = (u16*)(ws + 50331648);
  u16* w1T  = (u16*)(ws + 100663296);
  u16* pT   = (u16*)(ws + 101548032);
  // d_out doubles as q+k scratch until GEMM2 overwrites it
  u16* qbuf = (u16*)d_out;
  u16* kbuf = (u16*)((char*)d_out + 50331648);

  transpose_cvt_k<<<dim3(1152 / 32, 384 / 32), dim3(32, 8), 0, stream>>>(qkv_w, w1T, 384, 1152);
  transpose_cvt_k<<<dim3(384 / 32, 384 / 32), dim3(32, 8), 0, stream>>>(proj_w, pT, 384, 384);

  gemm_qkv_k<<<512, 512, 0, stream>>>(x, w1T, qkv_b, qbuf, kbuf, vbuf);
  attn_k<<<256 * 6 * 4, 256, 0, stream>>>(qbuf, kbuf, vbuf, gate, att);
  gemm_proj_k<<<512, 512, 0, stream>>>(att, pT, proj_b, out);
}

// Round 6
// 199.794 us; speedup vs baseline: 1.3142x; 1.3142x over previous
//
#include <hip/hip_runtime.h>
#include <hip/hip_bf16.h>

typedef unsigned short u16;
typedef __attribute__((ext_vector_type(8))) short short8;
typedef __attribute__((ext_vector_type(8))) unsigned short ushort8;
typedef __attribute__((ext_vector_type(4))) float f32x4;
typedef __attribute__((ext_vector_type(4))) float f4;

#define GLB_CAST(p) ((const __attribute__((address_space(1))) unsigned int*)(p))
#define LDS_CAST(p) ((__attribute__((address_space(3))) unsigned int*)(p))

__device__ __forceinline__ void gl_lds16(const void* g, void* l) {
  __builtin_amdgcn_global_load_lds(GLB_CAST(g), LDS_CAST(l), 16, 0, 0);
}

__device__ __forceinline__ u16 f2bf(float f) {
  __hip_bfloat16 b = __float2bfloat16(f);           // RNE
  return __builtin_bit_cast(u16, b);
}

// ---------------- prep: W [R][C] f32 -> Wt [C][R] bf16 ----------------
__global__ void transpose_cvt_k(const float* __restrict__ in,
                                u16* __restrict__ out, int R, int C) {
  __shared__ float tile[32][33];
  int c0 = blockIdx.x * 32, r0 = blockIdx.y * 32;
  int tx = threadIdx.x, ty = threadIdx.y;     // 32 x 8
#pragma unroll
  for (int i = 0; i < 32; i += 8)
    tile[ty + i][tx] = in[(size_t)(r0 + ty + i) * C + c0 + tx];
  __syncthreads();
#pragma unroll
  for (int i = 0; i < 32; i += 8)
    out[(size_t)(c0 + ty + i) * R + r0 + tx] = f2bf(tile[tx][ty + i]);
}

// ============ Unified streaming GEMM: A-resident + B ring-3, counted vmcnt ============
// EPI=1: qkv = x(f32)@w1T^T (+bias) -> q/k/v row-major [b,h,t,d] bf16; NT=9.
// EPI=2: out = att(bf16)@pT^T (+bias) -> f32 [M,384]; NT=3.
// Block: 512 thr (8 waves 2x4), one 128-row m-tile, A in LDS for the whole block.
// Steady loop: 1 raw s_barrier/step, vmcnt(2) counted waits, B prefetch depth 2 (L2-resident).
template <int EPI>
__global__ __launch_bounds__(512, 1) void gemm_k(
    const void* __restrict__ Av, const u16* __restrict__ Bt,
    const float* __restrict__ bias,
    u16* __restrict__ oQ, u16* __restrict__ oK, u16* __restrict__ oV,
    float* __restrict__ oF) {
  constexpr int K = 384;
  constexpr int NT = (EPI == 1) ? 9 : 3;
  __shared__ u16 As[128 * 384];          // 96KB, swizzled rows of 768B
  __shared__ u16 Bring[3][128 * 64];     // 3 x 16KB, swizzled rows of 128B
  __shared__ float bias_s[NT * 128];

  const int tid = threadIdx.x;
  const int m0 = blockIdx.x * 128;

  // bias -> LDS (keeps steady-loop vmem counting clean)
  for (int i = tid; i < NT * 128; i += 512) bias_s[i] = bias[i];

  // ---- B staging: linear LDS dest, inverse-swizzled global source ----
  const int br = tid >> 3;                       // 0..63 (rows br, br+64)
  const int bcs = ((tid & 7) ^ (br & 7)) * 8;    // swizzled source col (elems)
  auto stageB = [&](int slot, int tn, int kt) {
    const u16* s = Bt + (size_t)(tn * 128 + br) * K + kt * 64 + bcs;
    gl_lds16(s, (char*)Bring[slot] + tid * 16);
    gl_lds16(s + (size_t)64 * K, (char*)Bring[slot] + tid * 16 + 8192);
  };

  // prologue B prefetch for tile 0
  stageB(0, 0, 0);
  stageB(1, 0, 1);

  // ---- A staged once per block ----
  if (EPI == 1) {
    const float* X = (const float*)Av;
#pragma unroll
    for (int i = 0; i < 12; ++i) {
      int c = tid + i * 512;
      int row = c / 48, cc = c % 48;
      const float* src = X + (size_t)(m0 + row) * K + cc * 8;
      f4 a = *(const f4*)src;
      f4 b = *(const f4*)(src + 4);
      ushort8 o;
#pragma unroll
      for (int j = 0; j < 4; ++j) { o[j] = f2bf(a[j]); o[4 + j] = f2bf(b[j]); }
      *(ushort8*)((char*)As + row * 768 + ((cc * 16) ^ ((row & 7) << 4))) = o;
    }
  } else {
    const u16* Ab = (const u16*)Av;
#pragma unroll
    for (int i = 0; i < 12; ++i) {
      int c = tid + i * 512;
      int row = c / 48, cc = c % 48;
      int cs = cc ^ (row & 7);
      gl_lds16(Ab + (size_t)(m0 + row) * K + cs * 8, (char*)As + c * 16);
    }
  }
  __syncthreads();   // full drain once; steady loop uses raw barriers

  const int lane = tid & 63, wid = tid >> 6;
  const int lo = lane & 15, hi = lane >> 4;
  const int wr = wid >> 2, wc = wid & 3;         // wave tile: 64m x 32n
  const int akey = (lo & 7) << 4;
  int abase[4];
#pragma unroll
  for (int m = 0; m < 4; ++m) abase[m] = (wr * 64 + m * 16 + lo) * 768;
  const int bbase = (wc * 32 + lo) * 128;        // + n*2048

  const f32x4 Z4 = {0.f, 0.f, 0.f, 0.f};

  for (int t = 0; t < NT; ++t) {
    float bs[2];
    bs[0] = bias_s[t * 128 + wc * 32 + lo];
    bs[1] = bias_s[t * 128 + wc * 32 + 16 + lo];
    f32x4 acc[4][2];
#pragma unroll
    for (int m = 0; m < 4; ++m) { acc[m][0] = Z4; acc[m][1] = Z4; }

#pragma unroll
    for (int kt = 0; kt < 6; ++kt) {
      // counted wait: B(t,kt) is the oldest outstanding; keep 2 younger in flight
      if (kt == 5) asm volatile("s_waitcnt vmcnt(0)" ::: "memory");
      else         asm volatile("s_waitcnt vmcnt(2)" ::: "memory");
      __builtin_amdgcn_s_barrier();
      __builtin_amdgcn_sched_barrier(0);

      const char* bB = (const char*)Bring[kt % 3];
      short8 af[4][2], bf[2][2];
#pragma unroll
      for (int m = 0; m < 4; ++m)
#pragma unroll
        for (int s = 0; s < 2; ++s)
          af[m][s] = *(const short8*)((const char*)As + abase[m] +
                                      ((kt * 128 + s * 64 + hi * 16) ^ akey));
#pragma unroll
      for (int n = 0; n < 2; ++n)
#pragma unroll
        for (int s = 0; s < 2; ++s)
          bf[n][s] = *(const short8*)(bB + bbase + n * 2048 +
                                      ((s * 64 + hi * 16) ^ akey));

      if (kt < 4) stageB((kt + 2) % 3, t, kt + 2);   // depth-2 prefetch

      __builtin_amdgcn_s_setprio(1);
#pragma unroll
      for (int s = 0; s < 2; ++s)
#pragma unroll
        for (int m = 0; m < 4; ++m)
#pragma unroll
          for (int n = 0; n < 2; ++n)
            acc[m][n] = __builtin_amdgcn_mfma_f32_16x16x32_bf16(
                af[m][s], bf[n][s], acc[m][n], 0, 0, 0);
      __builtin_amdgcn_s_setprio(0);
    }

    // ---- epilogue (stores issued BEFORE boundary prefetch: older in vmcnt order) ----
    if (EPI == 1) {
      const int region = t / 3;
      u16* dst = (region == 0) ? oQ : ((region == 1) ? oK : oV);
      const int colb = (t % 3) * 128 + wc * 32 + lo;
#pragma unroll
      for (int n = 0; n < 2; ++n) {
        int hc = colb + n * 16;
        int hh = hc >> 6, d = hc & 63;
#pragma unroll
        for (int m = 0; m < 4; ++m)
#pragma unroll
          for (int rr = 0; rr < 4; ++rr) {
            int gm = m0 + wr * 64 + m * 16 + hi * 4 + rr;
            dst[(((size_t)((gm >> 8) * 6 + hh) << 8 | (gm & 255)) << 6) + d] =
                f2bf(acc[m][n][rr] + bs[n]);
          }
      }
    } else {
      const int colb = t * 128 + wc * 32 + lo;
#pragma unroll
      for (int m = 0; m < 4; ++m)
#pragma unroll
        for (int rr = 0; rr < 4; ++rr) {
          int gm = m0 + wr * 64 + m * 16 + hi * 4 + rr;
#pragma unroll
          for (int n = 0; n < 2; ++n)
            oF[(size_t)gm * 384 + colb + n * 16] = acc[m][n][rr] + bs[n];
        }
    }

    if (t + 1 < NT) {      // boundary prefetch for next tile's kt=0,1
      stageB(0, t + 1, 0);
      stageB(1, t + 1, 1);
    }
  }
}

// ---------------- windowed causal attention (V row-major, transpose at staging) ----------------
__global__ __launch_bounds__(256) void attn_k(
    const u16* __restrict__ Qb, const u16* __restrict__ Kb,
    const u16* __restrict__ Vb, const float* __restrict__ gate,
    u16* __restrict__ Ao) {
  __shared__ u16 Ks[128 * 64];      // [key][d]   swizzled, 16KB
  __shared__ u16 Vs[64 * 128];      // [d][key]   swizzled, 16KB
  __shared__ u16 Ps[4][16 * 128];   // per-wave P [q][key] swizzled, 16KB
  const int bx = blockIdx.x;
  const int qt = bx & 3, bh = bx >> 2;
  const int h = bh % 6, b = bh / 6;
  const int i0 = qt * 64, j0 = i0 - 64;
  const int tid = threadIdx.x, w = tid >> 6, lane = tid & 63;
  const int lo = lane & 15, hi = lane >> 4;

  const u16* Kh = Kb + (size_t)bh * (256 * 64);
  const u16* Vh = Vb + (size_t)bh * (256 * 64);
  const u16* Qh = Qb + (size_t)bh * (256 * 64);

#pragma unroll
  for (int it = 0; it < 4; ++it) {
    int chunk = tid + it * 256;
    int row = chunk >> 3, cc = chunk & 7;
    int csrc = cc ^ (row & 7);
    int j = j0 + row; if (j < 0) j = 0;
    gl_lds16(Kh + j * 64 + csrc * 8, Ks + chunk * 8);
  }
#pragma unroll
  for (int it = 0; it < 4; ++it) {
    int c = tid + it * 256;
    int dc = c >> 7;
    int j = c & 127;
    int jj = j0 + j; if (jj < 0) jj = 0;
    ushort8 v = *(const ushort8*)(Vh + jj * 64 + dc * 8);
#pragma unroll
    for (int e = 0; e < 8; ++e) {
      int d = dc * 8 + e;
      *(u16*)((char*)Vs + ((d * 256 + 2 * j) ^ ((d & 7) << 4))) = v[e];
    }
  }

  const int iq = i0 + w * 16 + lo;
  short8 aq0 = *(const short8*)(Qh + iq * 64 + hi * 8);
  short8 aq1 = *(const short8*)(Qh + iq * 64 + 32 + hi * 8);

  __syncthreads();

  const f32x4 Z4 = {0.f, 0.f, 0.f, 0.f};
  f32x4 accS[8];
#pragma unroll
  for (int t = 0; t < 8; ++t) accS[t] = Z4;
#pragma unroll
  for (int t = 0; t < 8; ++t) {
    int key = t * 16 + lo;
    int base = key * 128;
    int sw = (key & 7) << 4;
    short8 bk0 = *(const short8*)((const char*)Ks + ((base + hi * 16) ^ sw));
    short8 bk1 = *(const short8*)((const char*)Ks + ((base + 64 + hi * 16) ^ sw));
    accS[t] = __builtin_amdgcn_mfma_f32_16x16x32_bf16(aq0, bk0, accS[t], 0, 0, 0);
    accS[t] = __builtin_amdgcn_mfma_f32_16x16x32_bf16(aq1, bk1, accS[t], 0, 0, 0);
  }

  float pv[4][8];
  float rinv[4];
#pragma unroll
  for (int r = 0; r < 4; ++r) {
    int i = i0 + w * 16 + hi * 4 + r;
    float mx = -1e30f;
    float vals[8];
#pragma unroll
    for (int t = 0; t < 8; ++t) {
      int j = j0 + t * 16 + lo;
      float s = accS[t][r] * 0.125f;
      bool ok = (j >= 0) && (j <= i) && (j >= i - 64);
      vals[t] = ok ? s : -1e30f;
      mx = fmaxf(mx, vals[t]);
    }
#pragma unroll
    for (int off = 1; off < 16; off <<= 1) mx = fmaxf(mx, __shfl_xor(mx, off));
    float sum = 0.f;
#pragma unroll
    for (int t = 0; t < 8; ++t) {
      float p = __expf(vals[t] - mx);
      pv[r][t] = p;
      sum += p;
    }
#pragma unroll
    for (int off = 1; off < 16; off <<= 1) sum += __shfl_xor(sum, off);
    rinv[r] = 1.0f / sum;
  }

  u16* Pw = Ps[w];
#pragma unroll
  for (int r = 0; r < 4; ++r) {
    int ql = hi * 4 + r;
    int sw = (ql & 7) << 4;
#pragma unroll
    for (int t = 0; t < 8; ++t) {
      int off = (ql * 256 + (t * 16 + lo) * 2) ^ sw;
      *(u16*)((char*)Pw + off) = f2bf(pv[r][t]);
    }
  }

  f32x4 accO[4];
#pragma unroll
  for (int dt = 0; dt < 4; ++dt) accO[dt] = Z4;
#pragma unroll
  for (int ks = 0; ks < 4; ++ks) {
    int offA = (lo * 256 + ks * 64 + hi * 16) ^ ((lo & 7) << 4);
    short8 ap = *(const short8*)((const char*)Pw + offA);
#pragma unroll
    for (int dt = 0; dt < 4; ++dt) {
      int d = dt * 16 + lo;
      int offB = (d * 256 + ks * 64 + hi * 16) ^ ((d & 7) << 4);
      short8 bv = *(const short8*)((const char*)Vs + offB);
      accO[dt] = __builtin_amdgcn_mfma_f32_16x16x32_bf16(ap, bv, accO[dt], 0, 0, 0);
    }
  }

#pragma unroll
  for (int dt = 0; dt < 4; ++dt) {
    int d = dt * 16 + lo;
    float gg = gate[h * 64 + d];
#pragma unroll
    for (int r = 0; r < 4; ++r) {
      int i = i0 + w * 16 + hi * 4 + r;
      float v = accO[dt][r] * rinv[r] * gg;
      Ao[(size_t)(b * 256 + i) * 384 + h * 64 + d] = f2bf(v);
    }
  }
}

// ---------------- launch ----------------
extern "C" void kernel_launch(void* const* d_in, const int* in_sizes, int n_in,
                              void* d_out, int out_size, void* d_ws, size_t ws_size,
                              hipStream_t stream) {
  const float* x      = (const float*)d_in[0];
  const float* qkv_w  = (const float*)d_in[1];
  const float* qkv_b  = (const float*)d_in[2];
  const float* proj_w = (const float*)d_in[3];
  const float* proj_b = (const float*)d_in[4];
  const float* gate   = (const float*)d_in[5];
  float* out = (float*)d_out;

  // ws layout:
  //   [0, 50331648)            att (attention output, bf16)
  //   [50331648, 100663296)    v [b,h,t,d] bf16
  //   [100663296, 101548032)   w1T [1152,384] bf16
  //   [101548032, 101842944)   pT  [384,384]  bf16
  char* ws = (char*)d_ws;
  u16* att  = (u16*)ws;
  u16* vbuf = (u16*)(ws + 50331648);
  u16* w1T  = (u16*)(ws + 100663296);
  u16* pT   = (u16*)(ws + 101548032);
  u16* qbuf = (u16*)d_out;                         // d_out doubles as q+k scratch
  u16* kbuf = (u16*)((char*)d_out + 50331648);

  transpose_cvt_k<<<dim3(1152 / 32, 384 / 32), dim3(32, 8), 0, stream>>>(qkv_w, w1T, 384, 1152);
  transpose_cvt_k<<<dim3(384 / 32, 384 / 32), dim3(32, 8), 0, stream>>>(proj_w, pT, 384, 384);

  gemm_k<1><<<512, 512, 0, stream>>>(x, w1T, qkv_b, qbuf, kbuf, vbuf, nullptr);
  attn_k<<<256 * 6 * 4, 256, 0, stream>>>(qbuf, kbuf, vbuf, gate, att);
  gemm_k<2><<<512, 512, 0, stream>>>(att, pT, proj_b, nullptr, nullptr, nullptr, out);
}

// Round 7
// 196.468 us; speedup vs baseline: 1.3364x; 1.0169x over previous
//
#include <hip/hip_runtime.h>
#include <hip/hip_bf16.h>

typedef unsigned short u16;
typedef __attribute__((ext_vector_type(8))) short short8;
typedef __attribute__((ext_vector_type(8))) unsigned short ushort8;
typedef __attribute__((ext_vector_type(4))) float f32x4;
typedef __attribute__((ext_vector_type(4))) float f4;

#define GLB_CAST(p) ((const __attribute__((address_space(1))) unsigned int*)(p))
#define LDS_CAST(p) ((__attribute__((address_space(3))) unsigned int*)(p))

__device__ __forceinline__ void gl_lds16(const void* g, void* l) {
  __builtin_amdgcn_global_load_lds(GLB_CAST(g), LDS_CAST(l), 16, 0, 0);
}

__device__ __forceinline__ u16 f2bf(float f) {
  __hip_bfloat16 b = __float2bfloat16(f);           // RNE
  return __builtin_bit_cast(u16, b);
}

// ---------------- prep: W [R][C] f32 -> Wt [C][R] bf16 ----------------
__global__ void transpose_cvt_k(const float* __restrict__ in,
                                u16* __restrict__ out, int R, int C) {
  __shared__ float tile[32][33];
  int c0 = blockIdx.x * 32, r0 = blockIdx.y * 32;
  int tx = threadIdx.x, ty = threadIdx.y;     // 32 x 8
#pragma unroll
  for (int i = 0; i < 32; i += 8)
    tile[ty + i][tx] = in[(size_t)(r0 + ty + i) * C + c0 + tx];
  __syncthreads();
#pragma unroll
  for (int i = 0; i < 32; i += 8)
    out[(size_t)(c0 + ty + i) * R + r0 + tx] = f2bf(tile[tx][ty + i]);
}

// ========== Barrier-free streaming GEMM: A-resident LDS + wave-private B ring ==========
// EPI=1: qkv = x(f32)@w1T^T (+bias) -> q/k/v row-major [b,h,t,d] bf16; NT=9 col-tiles.
// EPI=2: out = att(bf16)@pT^T (+bias) -> f32 [M,384]; NT=3.
// Block 512 thr = 8 waves (2 wr x 4 wc), wave tile 64m x 32n, BK=32 (12 kt/tile).
// A [128x384] staged once (one __syncthreads). B: per-wave-private 3-slot ring
// (2KB slots), depth-2 prefetch, per-wave counted vmcnt — NO barriers in loop.
template <int EPI>
__global__ __launch_bounds__(512, 1) void gemm_k(
    const void* __restrict__ Av, const u16* __restrict__ Bt,
    const float* __restrict__ bias,
    u16* __restrict__ oQ, u16* __restrict__ oK, u16* __restrict__ oV,
    float* __restrict__ oF) {
  constexpr int K = 384;
  constexpr int NT = (EPI == 1) ? 9 : 3;
  __shared__ u16 As[128 * 384];        // 96KB, swizzled rows of 768B
  __shared__ u16 Bs[8][3][1024];       // 48KB: per-wave 3 slots of [32col][32k]
  __shared__ float bias_s[NT * 128];

  const int tid = threadIdx.x;
  const int m0 = blockIdx.x * 128;
  const int lane = tid & 63, wid = tid >> 6;
  const int lo = lane & 15, hi = lane >> 4;
  const int wr = wid >> 2, wc = wid & 3;

  for (int i = tid; i < NT * 128; i += 512) bias_s[i] = bias[i];

  // ---- wave-private B staging: slot [col][k] = [32][32] bf16, 64B rows ----
  // lane l writes slot bytes l*16 (+1024): col = r*16 + l/4, k = (l&3)*8
  const int bcol = wc * 32 + (lane >> 2);
  const int bko = (lane & 3) * 8;
  char* const slot_l = (char*)&Bs[0][0][0] + wid * 6144 + lane * 16;
  auto stageB = [&](int slot, int tn, int kt) {
    const u16* s = Bt + (size_t)(tn * 128 + bcol) * K + kt * 32 + bko;
    char* d = slot_l + slot * 2048;
    gl_lds16(s, d);
    gl_lds16(s + 16 * K, d + 1024);
  };

  stageB(0, 0, 0);
  stageB(1, 0, 1);

  // ---- A staged once ----
  if (EPI == 1) {
    const float* X = (const float*)Av;
#pragma unroll
    for (int i = 0; i < 12; ++i) {
      int c = tid + i * 512;
      int row = c / 48, cc = c % 48;
      const float* src = X + (size_t)(m0 + row) * K + cc * 8;
      f4 a = *(const f4*)src;
      f4 b = *(const f4*)(src + 4);
      ushort8 o;
#pragma unroll
      for (int j = 0; j < 4; ++j) { o[j] = f2bf(a[j]); o[4 + j] = f2bf(b[j]); }
      *(ushort8*)((char*)As + row * 768 + ((cc * 16) ^ ((row & 7) << 4))) = o;
    }
  } else {
    const u16* Ab = (const u16*)Av;
#pragma unroll
    for (int i = 0; i < 12; ++i) {
      int c = tid + i * 512;
      int row = c / 48, cc = c % 48;
      int cs = cc ^ (row & 7);
      gl_lds16(Ab + (size_t)(m0 + row) * K + cs * 8, (char*)As + c * 16);
    }
  }
  __syncthreads();    // the only barrier: A ready, prologue B drained

  const int akey = (lo & 7) << 4;
  int abase[4];
#pragma unroll
  for (int m = 0; m < 4; ++m) abase[m] = (wr * 64 + m * 16 + lo) * 768;
  const int bbase = lo * 64 + hi * 16;     // [col=n*16+lo][k] 64B rows: +n*1024
  const char* const Asc = (const char*)As;
  const char* const sb0 = (const char*)&Bs[0][0][0] + wid * 6144;

  // epilogue per-thread row parts
  int rp[4][4];
#pragma unroll
  for (int m = 0; m < 4; ++m)
#pragma unroll
    for (int rr = 0; rr < 4; ++rr) {
      int gm = m0 + wr * 64 + m * 16 + hi * 4 + rr;
      rp[m][rr] = (EPI == 1) ? ((gm >> 8) * 98304 + (gm & 255) * 64)  // b*6*16384 + t*64
                             : gm * 384;
    }

  const f32x4 Z4 = {0.f, 0.f, 0.f, 0.f};

  for (int t = 0; t < NT; ++t) {
    f32x4 acc[4][2];
#pragma unroll
    for (int m = 0; m < 4; ++m) { acc[m][0] = Z4; acc[m][1] = Z4; }

#pragma unroll
    for (int kt = 0; kt < 12; ++kt) {
      // per-wave counted wait: slot(kt) ready; keep depth-2 pipeline alive.
      // kt==0 also retires prev tile's 32 epilogue stores (in-order vmcnt).
      if (kt == 0) asm volatile("s_waitcnt vmcnt(4)" ::: "memory");
      else         asm volatile("s_waitcnt vmcnt(2)" ::: "memory");

      const char* sb = sb0 + (kt % 3) * 2048;
      short8 af[4], bf[2];
#pragma unroll
      for (int m = 0; m < 4; ++m)
        af[m] = *(const short8*)(Asc + abase[m] + ((kt * 64 + hi * 16) ^ akey));
      bf[0] = *(const short8*)(sb + bbase);
      bf[1] = *(const short8*)(sb + 1024 + bbase);

      if (kt < 10)           stageB((kt + 2) % 3, t, kt + 2);
      else if (t + 1 < NT)   stageB((kt + 2) % 3, t + 1, kt - 10);

      __builtin_amdgcn_s_setprio(1);
#pragma unroll
      for (int m = 0; m < 4; ++m) {
        acc[m][0] = __builtin_amdgcn_mfma_f32_16x16x32_bf16(af[m], bf[0], acc[m][0], 0, 0, 0);
        acc[m][1] = __builtin_amdgcn_mfma_f32_16x16x32_bf16(af[m], bf[1], acc[m][1], 0, 0, 0);
      }
      __builtin_amdgcn_s_setprio(0);
    }

    // ---- epilogue (stores are fire-and-forget; retired by next tile's vmcnt(4)) ----
    float bs0 = bias_s[t * 128 + wc * 32 + lo];
    float bs1 = bias_s[t * 128 + wc * 32 + 16 + lo];
    if (EPI == 1) {
      int r3 = t / 3;
      u16* dst = (r3 == 0) ? oQ : ((r3 == 1) ? oK : oV);
      int hc0 = (t - r3 * 3) * 128 + wc * 32 + lo;
      int cp0 = ((hc0 >> 6) << 14) + (hc0 & 63);       // hh*16384 + d
      int hc1 = hc0 + 16;
      int cp1 = ((hc1 >> 6) << 14) + (hc1 & 63);
#pragma unroll
      for (int m = 0; m < 4; ++m)
#pragma unroll
        for (int rr = 0; rr < 4; ++rr) {
          dst[(size_t)(rp[m][rr] + cp0)] = f2bf(acc[m][0][rr] + bs0);
          dst[(size_t)(rp[m][rr] + cp1)] = f2bf(acc[m][1][rr] + bs1);
        }
    } else {
      int colb = t * 128 + wc * 32 + lo;
#pragma unroll
      for (int m = 0; m < 4; ++m)
#pragma unroll
        for (int rr = 0; rr < 4; ++rr) {
          oF[(size_t)(rp[m][rr] + colb)] = acc[m][0][rr] + bs0;
          oF[(size_t)(rp[m][rr] + colb + 16)] = acc[m][1][rr] + bs1;
        }
    }
  }
}

// ---------------- windowed causal attention (V row-major, transpose at staging) ----------------
__global__ __launch_bounds__(256) void attn_k(
    const u16* __restrict__ Qb, const u16* __restrict__ Kb,
    const u16* __restrict__ Vb, const float* __restrict__ gate,
    u16* __restrict__ Ao) {
  __shared__ u16 Ks[128 * 64];      // [key][d]   swizzled, 16KB
  __shared__ u16 Vs[64 * 128];      // [d][key]   swizzled, 16KB
  __shared__ u16 Ps[4][16 * 128];   // per-wave P [q][key] swizzled, 16KB
  const int bx = blockIdx.x;
  const int qt = bx & 3, bh = bx >> 2;
  const int h = bh % 6, b = bh / 6;
  const int i0 = qt * 64, j0 = i0 - 64;
  const int tid = threadIdx.x, w = tid >> 6, lane = tid & 63;
  const int lo = lane & 15, hi = lane >> 4;

  const u16* Kh = Kb + (size_t)bh * (256 * 64);
  const u16* Vh = Vb + (size_t)bh * (256 * 64);
  const u16* Qh = Qb + (size_t)bh * (256 * 64);

#pragma unroll
  for (int it = 0; it < 4; ++it) {
    int chunk = tid + it * 256;
    int row = chunk >> 3, cc = chunk & 7;
    int csrc = cc ^ (row & 7);
    int j = j0 + row; if (j < 0) j = 0;
    gl_lds16(Kh + j * 64 + csrc * 8, Ks + chunk * 8);
  }
#pragma unroll
  for (int it = 0; it < 4; ++it) {
    int c = tid + it * 256;
    int dc = c >> 7;
    int j = c & 127;
    int jj = j0 + j; if (jj < 0) jj = 0;
    ushort8 v = *(const ushort8*)(Vh + jj * 64 + dc * 8);
#pragma unroll
    for (int e = 0; e < 8; ++e) {
      int d = dc * 8 + e;
      *(u16*)((char*)Vs + ((d * 256 + 2 * j) ^ ((d & 7) << 4))) = v[e];
    }
  }

  const int iq = i0 + w * 16 + lo;
  short8 aq0 = *(const short8*)(Qh + iq * 64 + hi * 8);
  short8 aq1 = *(const short8*)(Qh + iq * 64 + 32 + hi * 8);

  __syncthreads();

  const f32x4 Z4 = {0.f, 0.f, 0.f, 0.f};
  f32x4 accS[8];
#pragma unroll
  for (int t = 0; t < 8; ++t) accS[t] = Z4;
#pragma unroll
  for (int t = 0; t < 8; ++t) {
    int key = t * 16 + lo;
    int base = key * 128;
    int sw = (key & 7) << 4;
    short8 bk0 = *(const short8*)((const char*)Ks + ((base + hi * 16) ^ sw));
    short8 bk1 = *(const short8*)((const char*)Ks + ((base + 64 + hi * 16) ^ sw));
    accS[t] = __builtin_amdgcn_mfma_f32_16x16x32_bf16(aq0, bk0, accS[t], 0, 0, 0);
    accS[t] = __builtin_amdgcn_mfma_f32_16x16x32_bf16(aq1, bk1, accS[t], 0, 0, 0);
  }

  float pv[4][8];
  float rinv[4];
#pragma unroll
  for (int r = 0; r < 4; ++r) {
    int i = i0 + w * 16 + hi * 4 + r;
    float mx = -1e30f;
    float vals[8];
#pragma unroll
    for (int t = 0; t < 8; ++t) {
      int j = j0 + t * 16 + lo;
      float s = accS[t][r] * 0.125f;
      bool ok = (j >= 0) && (j <= i) && (j >= i - 64);
      vals[t] = ok ? s : -1e30f;
      mx = fmaxf(mx, vals[t]);
    }
#pragma unroll
    for (int off = 1; off < 16; off <<= 1) mx = fmaxf(mx, __shfl_xor(mx, off));
    float sum = 0.f;
#pragma unroll
    for (int t = 0; t < 8; ++t) {
      float p = __expf(vals[t] - mx);
      pv[r][t] = p;
      sum += p;
    }
#pragma unroll
    for (int off = 1; off < 16; off <<= 1) sum += __shfl_xor(sum, off);
    rinv[r] = 1.0f / sum;
  }

  u16* Pw = Ps[w];
#pragma unroll
  for (int r = 0; r < 4; ++r) {
    int ql = hi * 4 + r;
    int sw = (ql & 7) << 4;
#pragma unroll
    for (int t = 0; t < 8; ++t) {
      int off = (ql * 256 + (t * 16 + lo) * 2) ^ sw;
      *(u16*)((char*)Pw + off) = f2bf(pv[r][t]);
    }
  }

  f32x4 accO[4];
#pragma unroll
  for (int dt = 0; dt < 4; ++dt) accO[dt] = Z4;
#pragma unroll
  for (int ks = 0; ks < 4; ++ks) {
    int offA = (lo * 256 + ks * 64 + hi * 16) ^ ((lo & 7) << 4);
    short8 ap = *(const short8*)((const char*)Pw + offA);
#pragma unroll
    for (int dt = 0; dt < 4; ++dt) {
      int d = dt * 16 + lo;
      int offB = (d * 256 + ks * 64 + hi * 16) ^ ((d & 7) << 4);
      short8 bv = *(const short8*)((const char*)Vs + offB);
      accO[dt] = __builtin_amdgcn_mfma_f32_16x16x32_bf16(ap, bv, accO[dt], 0, 0, 0);
    }
  }

#pragma unroll
  for (int dt = 0; dt < 4; ++dt) {
    int d = dt * 16 + lo;
    float gg = gate[h * 64 + d];
#pragma unroll
    for (int r = 0; r < 4; ++r) {
      int i = i0 + w * 16 + hi * 4 + r;
      float v = accO[dt][r] * rinv[r] * gg;
      Ao[(size_t)(b * 256 + i) * 384 + h * 64 + d] = f2bf(v);
    }
  }
}

// ---------------- launch ----------------
extern "C" void kernel_launch(void* const* d_in, const int* in_sizes, int n_in,
                              void* d_out, int out_size, void* d_ws, size_t ws_size,
                              hipStream_t stream) {
  const float* x      = (const float*)d_in[0];
  const float* qkv_w  = (const float*)d_in[1];
  const float* qkv_b  = (const float*)d_in[2];
  const float* proj_w = (const float*)d_in[3];
  const float* proj_b = (const float*)d_in[4];
  const float* gate   = (const float*)d_in[5];
  float* out = (float*)d_out;

  // ws layout:
  //   [0, 50331648)            att (attention output, bf16)
  //   [50331648, 100663296)    v [b,h,t,d] bf16
  //   [100663296, 101548032)   w1T [1152,384] bf16
  //   [101548032, 101842944)   pT  [384,384]  bf16
  char* ws = (char*)d_ws;
  u16* att  = (u16*)ws;
  u16* vbuf = (u16*)(ws + 50331648);
  u16* w1T  = (u16*)(ws + 100663296);
  u16* pT   = (u16*)(ws + 101548032);
  u16* qbuf = (u16*)d_out;                         // d_out doubles as q+k scratch
  u16* kbuf = (u16*)((char*)d_out + 50331648);

  transpose_cvt_k<<<dim3(1152 / 32, 384 / 32), dim3(32, 8), 0, stream>>>(qkv_w, w1T, 384, 1152);
  transpose_cvt_k<<<dim3(384 / 32, 384 / 32), dim3(32, 8), 0, stream>>>(proj_w, pT, 384, 384);

  gemm_k<1><<<512, 512, 0, stream>>>(x, w1T, qkv_b, qbuf, kbuf, vbuf, nullptr);
  attn_k<<<256 * 6 * 4, 256, 0, stream>>>(qbuf, kbuf, vbuf, gate, att);
  gemm_k<2><<<512, 512, 0, stream>>>(att, pT, proj_b, nullptr, nullptr, nullptr, out);
}

// Round 8
// 195.167 us; speedup vs baseline: 1.3453x; 1.0067x over previous
//
#include <hip/hip_runtime.h>
#include <hip/hip_bf16.h>

typedef unsigned short u16;
typedef __attribute__((ext_vector_type(8))) short short8;
typedef __attribute__((ext_vector_type(8))) unsigned short ushort8;
typedef __attribute__((ext_vector_type(4))) float f32x4;
typedef __attribute__((ext_vector_type(4))) float f4;

#define GLB_CAST(p) ((const __attribute__((address_space(1))) unsigned int*)(p))
#define LDS_CAST(p) ((__attribute__((address_space(3))) unsigned int*)(p))

__device__ __forceinline__ void gl_lds16(const void* g, void* l) {
  __builtin_amdgcn_global_load_lds(GLB_CAST(g), LDS_CAST(l), 16, 0, 0);
}

__device__ __forceinline__ u16 f2bf(float f) {
  __hip_bfloat16 b = __float2bfloat16(f);           // RNE
  return __builtin_bit_cast(u16, b);
}

// ---------------- prep: W [R][C] f32 -> Wt [C][R] bf16 ----------------
__global__ void transpose_cvt_k(const float* __restrict__ in,
                                u16* __restrict__ out, int R, int C) {
  __shared__ float tile[32][33];
  int c0 = blockIdx.x * 32, r0 = blockIdx.y * 32;
  int tx = threadIdx.x, ty = threadIdx.y;     // 32 x 8
#pragma unroll
  for (int i = 0; i < 32; i += 8)
    tile[ty + i][tx] = in[(size_t)(r0 + ty + i) * C + c0 + tx];
  __syncthreads();
#pragma unroll
  for (int i = 0; i < 32; i += 8)
    out[(size_t)(c0 + ty + i) * R + r0 + tx] = f2bf(tile[tx][ty + i]);
}

// ========== Barrier-free streaming GEMM: 64-row A-resident + wave-private B ring ==========
// EPI=1: qkv = x(f32)@w1T^T (+bias) -> q/k/v row-major [b,h,t,d] bf16; NT=9 col-tiles.
// EPI=2: out = att(bf16)@pT^T (+bias) -> f32 [M,384]; NT=3.
// Block 256 thr = 4 waves, wave tile 64m x 32n, BK=32 (12 kt/tile).
// A [64x384] staged once (one __syncthreads). B: per-wave-private 3-slot ring,
// quarter-wave-conflict-free swizzle, depth-2 prefetch, per-wave counted vmcnt.
// LDS ~77KB -> 2 blocks/CU (4 waves/SIMD total) for cross-block latency hiding.
template <int EPI>
__global__ __launch_bounds__(256, 2) void gemm_k(
    const void* __restrict__ Av, const u16* __restrict__ Bt,
    const float* __restrict__ bias,
    u16* __restrict__ oQ, u16* __restrict__ oK, u16* __restrict__ oV,
    float* __restrict__ oF) {
  constexpr int K = 384;
  constexpr int NT = (EPI == 1) ? 9 : 3;
  __shared__ u16 As[64 * 384];         // 48KB, swizzled rows of 768B
  __shared__ u16 Bs[4][3][1024];       // 24KB: per-wave 3 slots [32col][32k]
  __shared__ float bias_s[NT * 128];

  const int tid = threadIdx.x;
  const int m0 = blockIdx.x * 64;
  const int lane = tid & 63, wid = tid >> 6;   // wid = wc (4 waves x 32 cols)
  const int lo = lane & 15, hi = lane >> 4;
  const int wc = wid;

  for (int i = tid; i < NT * 128; i += 256) bias_s[i] = bias[i];

  // ---- B staging: slot [32col][32k], pos p holds chunk c = p ^ ((col>>1)&3) ----
  // lane l -> col = l>>2 (and +16 for second gl_lds), pos p = l&3; key = (l>>3)&3
  const int bcol = wc * 32 + (lane >> 2);
  const int bc = ((lane & 3) ^ ((lane >> 3) & 3)) * 8;   // source k-offset (elems)
  char* const slot_l = (char*)&Bs[0][0][0] + wid * 6144 + lane * 16;
  auto stageB = [&](int slot, int tn, int kt) {
    const u16* s = Bt + (size_t)(tn * 128 + bcol) * K + kt * 32 + bc;
    char* d = slot_l + slot * 2048;
    gl_lds16(s, d);
    gl_lds16(s + 16 * K, d + 1024);    // cols +16, same key ((col+16)>>1 & 3 == key)
  };

  stageB(0, 0, 0);
  stageB(1, 0, 1);

  // ---- A staged once: rows of 768B, chunk q holds k-chunk q ^ (row&7) ----
  if (EPI == 1) {
    const float* X = (const float*)Av;
#pragma unroll
    for (int i = 0; i < 12; ++i) {
      int c = tid + i * 256;           // 3072 chunks of 16B
      int row = c / 48, cc = c % 48;
      const float* src = X + (size_t)(m0 + row) * K + cc * 8;
      f4 a = *(const f4*)src;
      f4 b = *(const f4*)(src + 4);
      ushort8 o;
#pragma unroll
      for (int j = 0; j < 4; ++j) { o[j] = f2bf(a[j]); o[4 + j] = f2bf(b[j]); }
      *(ushort8*)((char*)As + row * 768 + ((cc * 16) ^ ((row & 7) << 4))) = o;
    }
  } else {
    const u16* Ab = (const u16*)Av;
#pragma unroll
    for (int i = 0; i < 12; ++i) {
      int c = tid + i * 256;
      int row = c / 48, cc = c % 48;
      int cs = cc ^ (row & 7);
      gl_lds16(Ab + (size_t)(m0 + row) * K + cs * 8, (char*)As + c * 16);
    }
  }
  __syncthreads();    // full drain (A ready, prologue B slots 0/1 ready)

  const int akey = (lo & 7) << 4;
  const int rk = ((lo >> 1) & 3) << 4;       // B read key
  int abase[4];
#pragma unroll
  for (int m = 0; m < 4; ++m) abase[m] = (m * 16 + lo) * 768;
  const int bbase = lo * 64 + (hi * 16 ^ rk);
  const char* const Asc = (const char*)As;
  const char* const sb0 = (const char*)&Bs[0][0][0] + wid * 6144;

  // epilogue per-thread row parts
  int rp[4][4];
#pragma unroll
  for (int m = 0; m < 4; ++m)
#pragma unroll
    for (int rr = 0; rr < 4; ++rr) {
      int gm = m0 + m * 16 + hi * 4 + rr;
      rp[m][rr] = (EPI == 1) ? ((gm >> 8) * 98304 + (gm & 255) * 64)  // b*6*16384 + t*64
                             : gm * 384;
    }

  const f32x4 Z4 = {0.f, 0.f, 0.f, 0.f};

  for (int t = 0; t < NT; ++t) {
    f32x4 acc[4][2];
#pragma unroll
    for (int m = 0; m < 4; ++m) { acc[m][0] = Z4; acc[m][1] = Z4; }

#pragma unroll
    for (int kt = 0; kt < 12; ++kt) {
      // per-wave counted wait: slot(kt) ready, depth-2 pipeline stays live.
      if (kt == 0) asm volatile("s_waitcnt vmcnt(4)" ::: "memory");
      else         asm volatile("s_waitcnt vmcnt(2)" ::: "memory");

      const char* sb = sb0 + (kt % 3) * 2048;
      short8 af[4], bf[2];
#pragma unroll
      for (int m = 0; m < 4; ++m)
        af[m] = *(const short8*)(Asc + abase[m] + ((kt * 64 + hi * 16) ^ akey));
      bf[0] = *(const short8*)(sb + bbase);
      bf[1] = *(const short8*)(sb + 1024 + bbase);

      if (kt < 10)           stageB((kt + 2) % 3, t, kt + 2);
      else if (t + 1 < NT)   stageB((kt + 2) % 3, t + 1, kt - 10);

      __builtin_amdgcn_s_setprio(1);
#pragma unroll
      for (int m = 0; m < 4; ++m) {
        acc[m][0] = __builtin_amdgcn_mfma_f32_16x16x32_bf16(af[m], bf[0], acc[m][0], 0, 0, 0);
        acc[m][1] = __builtin_amdgcn_mfma_f32_16x16x32_bf16(af[m], bf[1], acc[m][1], 0, 0, 0);
      }
      __builtin_amdgcn_s_setprio(0);
    }

    // ---- epilogue (fire-and-forget stores; retired by next tile's vmcnt(4)) ----
    float bs0 = bias_s[t * 128 + wc * 32 + lo];
    float bs1 = bias_s[t * 128 + wc * 32 + 16 + lo];
    if (EPI == 1) {
      int r3 = t / 3;
      u16* dst = (r3 == 0) ? oQ : ((r3 == 1) ? oK : oV);
      int hc0 = (t - r3 * 3) * 128 + wc * 32 + lo;
      int cp0 = ((hc0 >> 6) << 14) + (hc0 & 63);       // hh*16384 + d
      int hc1 = hc0 + 16;
      int cp1 = ((hc1 >> 6) << 14) + (hc1 & 63);
#pragma unroll
      for (int m = 0; m < 4; ++m)
#pragma unroll
        for (int rr = 0; rr < 4; ++rr) {
          dst[(size_t)(rp[m][rr] + cp0)] = f2bf(acc[m][0][rr] + bs0);
          dst[(size_t)(rp[m][rr] + cp1)] = f2bf(acc[m][1][rr] + bs1);
        }
    } else {
      int colb = t * 128 + wc * 32 + lo;
#pragma unroll
      for (int m = 0; m < 4; ++m)
#pragma unroll
        for (int rr = 0; rr < 4; ++rr) {
          oF[(size_t)(rp[m][rr] + colb)] = acc[m][0][rr] + bs0;
          oF[(size_t)(rp[m][rr] + colb + 16)] = acc[m][1][rr] + bs1;
        }
    }
  }
}

// ---------------- windowed causal attention (V row-major, transpose at staging) ----------------
__global__ __launch_bounds__(256) void attn_k(
    const u16* __restrict__ Qb, const u16* __restrict__ Kb,
    const u16* __restrict__ Vb, const float* __restrict__ gate,
    u16* __restrict__ Ao) {
  __shared__ u16 Ks[128 * 64];      // [key][d]   swizzled, 16KB
  __shared__ u16 Vs[64 * 128];      // [d][key]   swizzled, 16KB
  __shared__ u16 Ps[4][16 * 128];   // per-wave P [q][key] swizzled, 16KB
  const int bx = blockIdx.x;
  const int qt = bx & 3, bh = bx >> 2;
  const int h = bh % 6, b = bh / 6;
  const int i0 = qt * 64, j0 = i0 - 64;
  const int tid = threadIdx.x, w = tid >> 6, lane = tid & 63;
  const int lo = lane & 15, hi = lane >> 4;

  const u16* Kh = Kb + (size_t)bh * (256 * 64);
  const u16* Vh = Vb + (size_t)bh * (256 * 64);
  const u16* Qh = Qb + (size_t)bh * (256 * 64);

#pragma unroll
  for (int it = 0; it < 4; ++it) {
    int chunk = tid + it * 256;
    int row = chunk >> 3, cc = chunk & 7;
    int csrc = cc ^ (row & 7);
    int j = j0 + row; if (j < 0) j = 0;
    gl_lds16(Kh + j * 64 + csrc * 8, Ks + chunk * 8);
  }
#pragma unroll
  for (int it = 0; it < 4; ++it) {
    int c = tid + it * 256;
    int dc = c >> 7;
    int j = c & 127;
    int jj = j0 + j; if (jj < 0) jj = 0;
    ushort8 v = *(const ushort8*)(Vh + jj * 64 + dc * 8);
#pragma unroll
    for (int e = 0; e < 8; ++e) {
      int d = dc * 8 + e;
      *(u16*)((char*)Vs + ((d * 256 + 2 * j) ^ ((d & 7) << 4))) = v[e];
    }
  }

  const int iq = i0 + w * 16 + lo;
  short8 aq0 = *(const short8*)(Qh + iq * 64 + hi * 8);
  short8 aq1 = *(const short8*)(Qh + iq * 64 + 32 + hi * 8);

  __syncthreads();

  const f32x4 Z4 = {0.f, 0.f, 0.f, 0.f};
  f32x4 accS[8];
#pragma unroll
  for (int t = 0; t < 8; ++t) accS[t] = Z4;
#pragma unroll
  for (int t = 0; t < 8; ++t) {
    int key = t * 16 + lo;
    int base = key * 128;
    int sw = (key & 7) << 4;
    short8 bk0 = *(const short8*)((const char*)Ks + ((base + hi * 16) ^ sw));
    short8 bk1 = *(const short8*)((const char*)Ks + ((base + 64 + hi * 16) ^ sw));
    accS[t] = __builtin_amdgcn_mfma_f32_16x16x32_bf16(aq0, bk0, accS[t], 0, 0, 0);
    accS[t] = __builtin_amdgcn_mfma_f32_16x16x32_bf16(aq1, bk1, accS[t], 0, 0, 0);
  }

  float pv[4][8];
  float rinv[4];
#pragma unroll
  for (int r = 0; r < 4; ++r) {
    int i = i0 + w * 16 + hi * 4 + r;
    float mx = -1e30f;
    float vals[8];
#pragma unroll
    for (int t = 0; t < 8; ++t) {
      int j = j0 + t * 16 + lo;
      float s = accS[t][r] * 0.125f;
      bool ok = (j >= 0) && (j <= i) && (j >= i - 64);
      vals[t] = ok ? s : -1e30f;
      mx = fmaxf(mx, vals[t]);
    }
#pragma unroll
    for (int off = 1; off < 16; off <<= 1) mx = fmaxf(mx, __shfl_xor(mx, off));
    float sum = 0.f;
#pragma unroll
    for (int t = 0; t < 8; ++t) {
      float p = __expf(vals[t] - mx);
      pv[r][t] = p;
      sum += p;
    }
#pragma unroll
    for (int off = 1; off < 16; off <<= 1) sum += __shfl_xor(sum, off);
    rinv[r] = 1.0f / sum;
  }

  u16* Pw = Ps[w];
#pragma unroll
  for (int r = 0; r < 4; ++r) {
    int ql = hi * 4 + r;
    int sw = (ql & 7) << 4;
#pragma unroll
    for (int t = 0; t < 8; ++t) {
      int off = (ql * 256 + (t * 16 + lo) * 2) ^ sw;
      *(u16*)((char*)Pw + off) = f2bf(pv[r][t]);
    }
  }

  f32x4 accO[4];
#pragma unroll
  for (int dt = 0; dt < 4; ++dt) accO[dt] = Z4;
#pragma unroll
  for (int ks = 0; ks < 4; ++ks) {
    int offA = (lo * 256 + ks * 64 + hi * 16) ^ ((lo & 7) << 4);
    short8 ap = *(const short8*)((const char*)Pw + offA);
#pragma unroll
    for (int dt = 0; dt < 4; ++dt) {
      int d = dt * 16 + lo;
      int offB = (d * 256 + ks * 64 + hi * 16) ^ ((d & 7) << 4);
      short8 bv = *(const short8*)((const char*)Vs + offB);
      accO[dt] = __builtin_amdgcn_mfma_f32_16x16x32_bf16(ap, bv, accO[dt], 0, 0, 0);
    }
  }

#pragma unroll
  for (int dt = 0; dt < 4; ++dt) {
    int d = dt * 16 + lo;
    float gg = gate[h * 64 + d];
#pragma unroll
    for (int r = 0; r < 4; ++r) {
      int i = i0 + w * 16 + hi * 4 + r;
      float v = accO[dt][r] * rinv[r] * gg;
      Ao[(size_t)(b * 256 + i) * 384 + h * 64 + d] = f2bf(v);
    }
  }
}

// ---------------- launch ----------------
extern "C" void kernel_launch(void* const* d_in, const int* in_sizes, int n_in,
                              void* d_out, int out_size, void* d_ws, size_t ws_size,
                              hipStream_t stream) {
  const float* x      = (const float*)d_in[0];
  const float* qkv_w  = (const float*)d_in[1];
  const float* qkv_b  = (const float*)d_in[2];
  const float* proj_w = (const float*)d_in[3];
  const float* proj_b = (const float*)d_in[4];
  const float* gate   = (const float*)d_in[5];
  float* out = (float*)d_out;

  // ws layout:
  //   [0, 50331648)            att (attention output, bf16)
  //   [50331648, 100663296)    v [b,h,t,d] bf16
  //   [100663296, 101548032)   w1T [1152,384] bf16
  //   [101548032, 101842944)   pT  [384,384]  bf16
  char* ws = (char*)d_ws;
  u16* att  = (u16*)ws;
  u16* vbuf = (u16*)(ws + 50331648);
  u16* w1T  = (u16*)(ws + 100663296);
  u16* pT   = (u16*)(ws + 101548032);
  u16* qbuf = (u16*)d_out;                         // d_out doubles as q+k scratch
  u16* kbuf = (u16*)((char*)d_out + 50331648);

  transpose_cvt_k<<<dim3(1152 / 32, 384 / 32), dim3(32, 8), 0, stream>>>(qkv_w, w1T, 384, 1152);
  transpose_cvt_k<<<dim3(384 / 32, 384 / 32), dim3(32, 8), 0, stream>>>(proj_w, pT, 384, 384);

  gemm_k<1><<<1024, 256, 0, stream>>>(x, w1T, qkv_b, qbuf, kbuf, vbuf, nullptr);
  attn_k<<<256 * 6 * 4, 256, 0, stream>>>(qbuf, kbuf, vbuf, gate, att);
  gemm_k<2><<<1024, 256, 0, stream>>>(att, pT, proj_b, nullptr, nullptr, nullptr, out);
}